// Round 3
// baseline (134.399 us; speedup 1.0000x reference)
//
#include <hip/hip_runtime.h>
#include <hip/hip_bf16.h>

#define NTOT   8192
#define BHALF  4096
#define DDIM   256
#define TEMP_INV 10.0f
#define BN     64
#define LDSTRIDE 264   // 256 + 8 pad: row stride 528B -> m-lanes 4 banks apart, 2-way only

typedef __attribute__((ext_vector_type(8))) short bf16x8_t;  // 8 bf16 = 4 VGPRs
typedef __attribute__((ext_vector_type(4))) float f32x4_t;   // MFMA C/D

__device__ inline unsigned short f2bf(float x) {
    __hip_bfloat16 h = __float2bfloat16(x);
    return __builtin_bit_cast(unsigned short, h);
}

// ---- kernel 1: normalize pair k (rows k and k+B), emit bf16 zn, posdot, zero s_arr ----
// one wave per pair k; grid 1024 x 256
__global__ void norm_pair_kernel(const float* __restrict__ zi,
                                 const float* __restrict__ zj,
                                 unsigned short* __restrict__ zn,
                                 float* __restrict__ posdot,
                                 float* __restrict__ s_arr) {
    int gtid = blockIdx.x * 256 + threadIdx.x;
    if (gtid < NTOT) s_arr[gtid] = 0.0f;   // completes before gemm (stream order)
    int k    = gtid >> 6;
    int lane = gtid & 63;
    float4 vi = reinterpret_cast<const float4*>(zi + (size_t)k * DDIM)[lane];
    float4 vj = reinterpret_cast<const float4*>(zj + (size_t)k * DDIM)[lane];
    float ssi = vi.x*vi.x + vi.y*vi.y + vi.z*vi.z + vi.w*vi.w;
    float ssj = vj.x*vj.x + vj.y*vj.y + vj.z*vj.z + vj.w*vj.w;
    float dot = vi.x*vj.x + vi.y*vj.y + vi.z*vj.z + vi.w*vj.w;
    #pragma unroll
    for (int off = 32; off >= 1; off >>= 1) {
        ssi += __shfl_xor(ssi, off);
        ssj += __shfl_xor(ssj, off);
        dot += __shfl_xor(dot, off);
    }
    float ri = 1.0f / fmaxf(sqrtf(ssi), 1e-8f);
    float rj = 1.0f / fmaxf(sqrtf(ssj), 1e-8f);
    ushort4 oi, oj;
    oi.x = f2bf(vi.x * ri); oi.y = f2bf(vi.y * ri);
    oi.z = f2bf(vi.z * ri); oi.w = f2bf(vi.w * ri);
    oj.x = f2bf(vj.x * rj); oj.y = f2bf(vj.y * rj);
    oj.z = f2bf(vj.z * rj); oj.w = f2bf(vj.w * rj);
    reinterpret_cast<ushort4*>(zn + (size_t)k * DDIM)[lane] = oi;
    reinterpret_cast<ushort4*>(zn + (size_t)(k + BHALF) * DDIM)[lane] = oj;
    if (lane == 0) posdot[k] = dot * ri * rj * TEMP_INV;
}

// ---- kernel 2: symmetric fused GEMM + exp-sum.
// Upper-triangular strips: row block bi (256 rows) x col strip cs (64 cols), cs >= 4*bi.
// 2112 blocks, 256 threads (4 waves x 64 rows, rf=4). Each exp contributes to its
// row-sum; off-diagonal strips also contribute to the column's row-sum (symmetry).
__global__ void __launch_bounds__(256, 2)
gemm_sym_kernel(const unsigned short* __restrict__ zn,
                float* __restrict__ s_arr) {
    __shared__ unsigned short ldsB[BN * LDSTRIDE];   // 33792 B

    // decode blockIdx.x -> (bi, cs) over the strip triangle (uniform scalar loop)
    int id = blockIdx.x;
    int bi = 0;
    while (id >= 128 - 4 * bi) { id -= 128 - 4 * bi; ++bi; }
    const int cs = 4 * bi + id;
    const int R0 = bi << 8;
    const int C0 = cs << 6;
    const bool isDiag = ((cs >> 2) == bi);

    const int tid  = threadIdx.x;
    const int lane = tid & 63;
    const int wv   = tid >> 6;        // 0..3 -> 64-row slice
    const int m    = lane & 15;
    const int quad = lane >> 4;

    // A fragments: rows R0 + wv*64 + rf*16 + m, k = kk*32 + quad*8 (+j)
    bf16x8_t afrag[4][8];
    #pragma unroll
    for (int rf = 0; rf < 4; ++rf) {
        const unsigned short* arow = zn + (size_t)(R0 + wv*64 + rf*16 + m) * DDIM;
        #pragma unroll
        for (int kk = 0; kk < 8; ++kk)
            afrag[rf][kk] = *reinterpret_cast<const bf16x8_t*>(arow + kk*32 + quad*8);
    }

    // stage B tile: 64 cols x 256 k = 2048 16B chunks over 256 threads
    #pragma unroll
    for (int s = 0; s < 8; ++s) {
        int ci = s * 256 + tid;
        int n = ci >> 5, c = ci & 31;
        bf16x8_t v = *reinterpret_cast<const bf16x8_t*>(zn + (size_t)(C0 + n) * DDIM + c * 8);
        *reinterpret_cast<bf16x8_t*>(&ldsB[n * LDSTRIDE + c * 8]) = v;
    }
    __syncthreads();

    float rowacc[4][4] = {{0.f,0.f,0.f,0.f},{0.f,0.f,0.f,0.f},
                          {0.f,0.f,0.f,0.f},{0.f,0.f,0.f,0.f}};

    #pragma unroll
    for (int cf = 0; cf < 4; ++cf) {
        f32x4_t cacc[4];
        #pragma unroll
        for (int rf = 0; rf < 4; ++rf) cacc[rf] = (f32x4_t){0.f,0.f,0.f,0.f};

        #pragma unroll
        for (int kk = 0; kk < 8; ++kk) {
            bf16x8_t b = *reinterpret_cast<const bf16x8_t*>(
                             &ldsB[(cf*16 + m) * LDSTRIDE + kk*32 + quad*8]);
            #pragma unroll
            for (int rf = 0; rf < 4; ++rf)
                cacc[rf] = __builtin_amdgcn_mfma_f32_16x16x32_bf16(
                    afrag[rf][kk], b, cacc[rf], 0, 0, 0);
        }

        // epilogue for this column fragment
        const int gc = C0 + cf*16 + m;
        float colsum = 0.f;
        #pragma unroll
        for (int rf = 0; rf < 4; ++rf) {
            #pragma unroll
            for (int r = 0; r < 4; ++r) {
                int gr = R0 + wv*64 + rf*16 + quad*4 + r;
                float e = __expf(cacc[rf][r] * TEMP_INV);
                if (isDiag && gr == gc) e = 0.f;
                rowacc[rf][r] += e;
                colsum += e;
            }
        }
        if (!isDiag) {
            // reduce over the 64 rows this wave covers (lanes differing in quad)
            colsum += __shfl_xor(colsum, 16);
            colsum += __shfl_xor(colsum, 32);
            if (quad == 0) atomicAdd(&s_arr[gc], colsum);
        }
    }

    // row-sum reduce over the 16 m-lanes sharing a row, one atomic per row
    #pragma unroll
    for (int rf = 0; rf < 4; ++rf)
        #pragma unroll
        for (int r = 0; r < 4; ++r) {
            float v = rowacc[rf][r];
            v += __shfl_xor(v, 1);
            v += __shfl_xor(v, 2);
            v += __shfl_xor(v, 4);
            v += __shfl_xor(v, 8);
            if (m == 0)
                atomicAdd(&s_arr[R0 + wv*64 + rf*16 + quad*4 + r], v);
        }
}

// ---- kernel 3: loss_k = log(s_k) - posdot[k%B]; masked mean -> scalar ----
__global__ void finalize_kernel(const float* __restrict__ s_arr,
                                const float* __restrict__ posdot,
                                const unsigned char* __restrict__ mask,
                                float* __restrict__ out) {
    int tid = threadIdx.x, lane = tid & 63, wv = tid >> 6;
    float tot = 0.f, cnt = 0.f;
    #pragma unroll
    for (int s = 0; s < NTOT / 1024; ++s) {
        int k = s * 1024 + tid;
        int kb = k & (BHALF - 1);
        if (mask[kb] != 0) {
            tot += __logf(s_arr[k]) - posdot[kb];
            cnt += 1.f;
        }
    }
    #pragma unroll
    for (int off = 32; off >= 1; off >>= 1) {
        tot += __shfl_xor(tot, off);
        cnt += __shfl_xor(cnt, off);
    }
    __shared__ float st[16], sc[16];
    if (lane == 0) { st[wv] = tot; sc[wv] = cnt; }
    __syncthreads();
    if (tid == 0) {
        float T = 0.f, C = 0.f;
        #pragma unroll
        for (int i = 0; i < 16; ++i) { T += st[i]; C += sc[i]; }
        out[0] = (C > 0.f) ? (T / fmaxf(C, 1.f)) : 0.f;
    }
}

extern "C" void kernel_launch(void* const* d_in, const int* in_sizes, int n_in,
                              void* d_out, int out_size, void* d_ws, size_t ws_size,
                              hipStream_t stream) {
    const float* zi = (const float*)d_in[0];
    const float* zj = (const float*)d_in[1];
    const unsigned char* mask = (const unsigned char*)d_in[2];
    float* out = (float*)d_out;

    // ws: [0,4MB) zn bf16; s_arr[8192] f32; posdot[4096] f32
    unsigned short* zn = (unsigned short*)d_ws;
    float* s_arr  = (float*)((char*)d_ws + (size_t)NTOT * DDIM * 2);
    float* posdot = s_arr + NTOT;

    norm_pair_kernel<<<dim3(1024), dim3(256), 0, stream>>>(zi, zj, zn, posdot, s_arr);
    gemm_sym_kernel<<<dim3(2112), dim3(256), 0, stream>>>(zn, s_arr);
    finalize_kernel<<<dim3(1), dim3(1024), 0, stream>>>(s_arr, posdot, mask, out);
}

// Round 4
// 111.121 us; speedup vs baseline: 1.2095x; 1.2095x over previous
//
#include <hip/hip_runtime.h>
#include <hip/hip_bf16.h>

#define NTOT   8192
#define BHALF  4096
#define DDIM   256
#define TEMP_INV 10.0f
#define SMOD   16     // column-strip split factor (strips per row-block shared by 16 blocks)
#define NPART  4      // partial copies of s_arr to spread atomic contention

typedef __attribute__((ext_vector_type(8))) short bf16x8_t;  // 8 bf16 = 4 VGPRs
typedef __attribute__((ext_vector_type(4))) float f32x4_t;   // MFMA C/D

__device__ inline unsigned short f2bf(float x) {
    __hip_bfloat16 h = __float2bfloat16(x);
    return __builtin_bit_cast(unsigned short, h);
}

// ---- kernel 1: normalize pair k (rows k, k+B) -> bf16 zn; posdot; zero s_part ----
__global__ void norm_pair_kernel(const float* __restrict__ zi,
                                 const float* __restrict__ zj,
                                 unsigned short* __restrict__ zn,
                                 float* __restrict__ posdot,
                                 float* __restrict__ s_part) {
    int gtid = blockIdx.x * 256 + threadIdx.x;
    if (gtid < NTOT * NPART) s_part[gtid] = 0.0f;   // done before gemm (stream order)
    int k    = gtid >> 6;
    int lane = gtid & 63;
    float4 vi = reinterpret_cast<const float4*>(zi + (size_t)k * DDIM)[lane];
    float4 vj = reinterpret_cast<const float4*>(zj + (size_t)k * DDIM)[lane];
    float ssi = vi.x*vi.x + vi.y*vi.y + vi.z*vi.z + vi.w*vi.w;
    float ssj = vj.x*vj.x + vj.y*vj.y + vj.z*vj.z + vj.w*vj.w;
    float dot = vi.x*vj.x + vi.y*vj.y + vi.z*vj.z + vi.w*vj.w;
    #pragma unroll
    for (int off = 32; off >= 1; off >>= 1) {
        ssi += __shfl_xor(ssi, off);
        ssj += __shfl_xor(ssj, off);
        dot += __shfl_xor(dot, off);
    }
    float ri = 1.0f / fmaxf(sqrtf(ssi), 1e-8f);
    float rj = 1.0f / fmaxf(sqrtf(ssj), 1e-8f);
    ushort4 oi, oj;
    oi.x = f2bf(vi.x * ri); oi.y = f2bf(vi.y * ri);
    oi.z = f2bf(vi.z * ri); oi.w = f2bf(vi.w * ri);
    oj.x = f2bf(vj.x * rj); oj.y = f2bf(vj.y * rj);
    oj.z = f2bf(vj.z * rj); oj.w = f2bf(vj.w * rj);
    reinterpret_cast<ushort4*>(zn + (size_t)k * DDIM)[lane] = oi;
    reinterpret_cast<ushort4*>(zn + (size_t)(k + BHALF) * DDIM)[lane] = oj;
    if (lane == 0) posdot[k] = dot * ri * rj * TEMP_INV;
}

// ---- kernel 2: symmetric fused GEMM + exp-sum, XOR-swizzled LDS, multi-strip ----
// Row block bi: 128 rows. Block (bi, s) handles col strips cs ≡ s (mod 16), cs >= 2bi.
// isDiag strip (cs>>1 == bi): full tile, zero self-sim, no mirror (both orientations
// computed directly). Non-diag: cols strictly above rows; mirror exp into col sums.
__global__ void __launch_bounds__(256)
gemm_sym_kernel(const unsigned short* __restrict__ zn,
                float* __restrict__ s_part) {
    __shared__ unsigned short ldsB[64 * 256];   // 32 KB, 16B chunks xor-swizzled
    __shared__ float colred[4][64];

    const int bi = blockIdx.x;        // 0..63
    const int s  = blockIdx.y;        // 0..15
    const int R0 = bi << 7;

    int cs0 = 2 * bi + ((s - 2 * bi) & (SMOD - 1));
    if (cs0 >= 128) return;           // no strips for this block (uniform exit)

    const int tid  = threadIdx.x;
    const int lane = tid & 63;
    const int wv   = tid >> 6;        // 0..3 -> 32-row slice
    const int m    = lane & 15;
    const int quad = lane >> 4;

    float* rowPart = s_part + (size_t)(s  & (NPART - 1)) * NTOT;
    float* colPart = s_part + (size_t)(bi & (NPART - 1)) * NTOT;

    // A fragments: rows R0 + wv*32 + rf*16 + m, loaded once, reused across strips
    bf16x8_t afrag[2][8];
    #pragma unroll
    for (int rf = 0; rf < 2; ++rf) {
        const unsigned short* arow = zn + (size_t)(R0 + wv*32 + rf*16 + m) * DDIM;
        #pragma unroll
        for (int kk = 0; kk < 8; ++kk)
            afrag[rf][kk] = *reinterpret_cast<const bf16x8_t*>(arow + kk*32 + quad*8);
    }

    float rowacc[2][4] = {{0.f,0.f,0.f,0.f},{0.f,0.f,0.f,0.f}};

    for (int cs = cs0; cs < 128; cs += SMOD) {
        const int C0 = cs << 6;
        const bool isDiag = ((cs >> 1) == bi);

        // stage B tile 64 rows x 256 k; chunk c of row r -> slot (c ^ (r&7))
        #pragma unroll
        for (int t = 0; t < 8; ++t) {
            int ci = t * 256 + tid;
            int r = ci >> 5, c = ci & 31;
            bf16x8_t v = *reinterpret_cast<const bf16x8_t*>(
                             zn + (size_t)(C0 + r) * DDIM + c * 8);
            *reinterpret_cast<bf16x8_t*>(&ldsB[r * 256 + ((c ^ (r & 7)) << 3)]) = v;
        }
        __syncthreads();   // staging done; also orders prev-iter colred reads vs writes

        #pragma unroll
        for (int cf = 0; cf < 4; ++cf) {
            f32x4_t cacc0 = (f32x4_t){0.f,0.f,0.f,0.f};
            f32x4_t cacc1 = (f32x4_t){0.f,0.f,0.f,0.f};
            #pragma unroll
            for (int kk = 0; kk < 8; ++kk) {
                bf16x8_t b = *reinterpret_cast<const bf16x8_t*>(
                    &ldsB[(cf*16 + m) * 256 + (((kk*4 + quad) ^ (m & 7)) << 3)]);
                cacc0 = __builtin_amdgcn_mfma_f32_16x16x32_bf16(afrag[0][kk], b, cacc0, 0, 0, 0);
                cacc1 = __builtin_amdgcn_mfma_f32_16x16x32_bf16(afrag[1][kk], b, cacc1, 0, 0, 0);
            }
            const int gc = C0 + cf*16 + m;
            float colsum = 0.f;
            #pragma unroll
            for (int r = 0; r < 4; ++r) {
                int gr0 = R0 + wv*32 + quad*4 + r;
                float e0 = __expf(cacc0[r] * TEMP_INV);
                float e1 = __expf(cacc1[r] * TEMP_INV);
                if (isDiag && gr0 == gc)        e0 = 0.f;
                if (isDiag && (gr0 + 16) == gc) e1 = 0.f;
                rowacc[0][r] += e0;
                rowacc[1][r] += e1;
                colsum += e0 + e1;
            }
            if (!isDiag) {
                colsum += __shfl_xor(colsum, 16);
                colsum += __shfl_xor(colsum, 32);
                if (quad == 0) colred[wv][cf*16 + m] = colsum;
            }
        }
        __syncthreads();   // colred complete; ldsB readers done (next staging safe)

        if (!isDiag && tid < 64)
            atomicAdd(&colPart[C0 + tid],
                      colred[0][tid] + colred[1][tid] + colred[2][tid] + colred[3][tid]);
    }

    // row totals: reduce over the 16 m-lanes sharing a row, one atomic per row
    #pragma unroll
    for (int rf = 0; rf < 2; ++rf)
        #pragma unroll
        for (int r = 0; r < 4; ++r) {
            float v = rowacc[rf][r];
            v += __shfl_xor(v, 1);
            v += __shfl_xor(v, 2);
            v += __shfl_xor(v, 4);
            v += __shfl_xor(v, 8);
            if (m == 0)
                atomicAdd(&rowPart[R0 + wv*32 + rf*16 + quad*4 + r], v);
        }
}

// ---- kernel 3: loss_k = log(sum_p s_part[p][k]) - posdot[k%B]; masked mean ----
__global__ void finalize_kernel(const float* __restrict__ s_part,
                                const float* __restrict__ posdot,
                                const unsigned char* __restrict__ mask,
                                float* __restrict__ out) {
    int tid = threadIdx.x, lane = tid & 63, wv = tid >> 6;
    float tot = 0.f, cnt = 0.f;
    #pragma unroll
    for (int si = 0; si < NTOT / 1024; ++si) {
        int k = si * 1024 + tid;
        int kb = k & (BHALF - 1);
        if (mask[kb] != 0) {
            float sk = s_part[k] + s_part[NTOT + k]
                     + s_part[2*NTOT + k] + s_part[3*NTOT + k];
            tot += __logf(sk) - posdot[kb];
            cnt += 1.f;
        }
    }
    #pragma unroll
    for (int off = 32; off >= 1; off >>= 1) {
        tot += __shfl_xor(tot, off);
        cnt += __shfl_xor(cnt, off);
    }
    __shared__ float st[16], sc[16];
    if (lane == 0) { st[wv] = tot; sc[wv] = cnt; }
    __syncthreads();
    if (tid == 0) {
        float T = 0.f, C = 0.f;
        #pragma unroll
        for (int i = 0; i < 16; ++i) { T += st[i]; C += sc[i]; }
        out[0] = (C > 0.f) ? (T / fmaxf(C, 1.f)) : 0.f;
    }
}

extern "C" void kernel_launch(void* const* d_in, const int* in_sizes, int n_in,
                              void* d_out, int out_size, void* d_ws, size_t ws_size,
                              hipStream_t stream) {
    const float* zi = (const float*)d_in[0];
    const float* zj = (const float*)d_in[1];
    const unsigned char* mask = (const unsigned char*)d_in[2];
    float* out = (float*)d_out;

    // ws: [0,4MB) zn bf16; s_part[4][8192] f32; posdot[4096] f32
    unsigned short* zn = (unsigned short*)d_ws;
    float* s_part = (float*)((char*)d_ws + (size_t)NTOT * DDIM * 2);
    float* posdot = s_part + NPART * NTOT;

    norm_pair_kernel<<<dim3(1024), dim3(256), 0, stream>>>(zi, zj, zn, posdot, s_part);
    gemm_sym_kernel<<<dim3(64, SMOD), dim3(256), 0, stream>>>(zn, s_part);
    finalize_kernel<<<dim3(1), dim3(1024), 0, stream>>>(s_part, posdot, mask, out);
}